// Round 1
// baseline (189.527 us; speedup 1.0000x reference)
//
#include <hip/hip_runtime.h>
#include <hip/hip_bf16.h>
#include <stdint.h>

#define NROWS 8192
#define DIM 512

typedef short bf16x8 __attribute__((ext_vector_type(8)));
typedef float f32x4 __attribute__((ext_vector_type(4)));

__device__ __forceinline__ unsigned short f2bf(float f) {
    union { float f; uint32_t u; } c; c.f = f;
    uint32_t u = c.u;
    return (unsigned short)((u + 0x7FFFu + ((u >> 16) & 1u)) >> 16);
}

__device__ __forceinline__ void gload16(const unsigned short* g, unsigned short* l) {
    __builtin_amdgcn_global_load_lds((const __attribute__((address_space(1))) void*)g,
                                     (__attribute__((address_space(3))) void*)l,
                                     16, 0, 0);
}

// ---------------- Kernel 1: L2-normalize rows, emit bf16 ----------------
__global__ __launch_bounds__(256) void knorm(const float* __restrict__ in,
                                             unsigned short* __restrict__ out) {
    const int row  = (blockIdx.x << 2) + (threadIdx.x >> 6);
    const int lane = threadIdx.x & 63;
    const float4* src = (const float4*)(in + (size_t)row * DIM);
    float4 a = src[lane];
    float4 b = src[lane + 64];
    float ss = a.x*a.x + a.y*a.y + a.z*a.z + a.w*a.w
             + b.x*b.x + b.y*b.y + b.z*b.z + b.w*b.w;
    #pragma unroll
    for (int m = 1; m < 64; m <<= 1) ss += __shfl_xor(ss, m);
    const float inv = 1.0f / sqrtf(ss);
    ushort4* dst = (ushort4*)(out + (size_t)row * DIM);
    ushort4 o;
    o.x = f2bf(a.x*inv); o.y = f2bf(a.y*inv); o.z = f2bf(a.z*inv); o.w = f2bf(a.w*inv);
    dst[lane] = o;
    o.x = f2bf(b.x*inv); o.y = f2bf(b.y*inv); o.z = f2bf(b.z*inv); o.w = f2bf(b.w*inv);
    dst[lane + 64] = o;
}

// ---------------- Kernel 2: fused E*E^T + exp + mask + row-reduce ----------------
// Tile 128x128, 4 waves (2x2, each 64x64), BK=64, K=512.
// LDS layout: linear [128][64] bf16 per tile, XOR-swizzled on the 16B-group
// axis: LDS(r, g) holds data(r, g ^ (r&7)). global_load_lds writes linearly,
// so the SOURCE address is inverse-swizzled; ds_reads apply the same XOR.
__global__ __launch_bounds__(256) void kgemm(const unsigned short* __restrict__ E,
                                             float* __restrict__ pos,
                                             float* __restrict__ neg) {
    __shared__ unsigned short lA[128 * 64];
    __shared__ unsigned short lB[128 * 64];

    const int tid = threadIdx.x;
    const int w = tid >> 6;
    const int l = tid & 63;
    const int bi = blockIdx.x >> 6;      // row tile
    const int bj = blockIdx.x & 63;      // col tile
    const int brow = bi << 7;
    const int bcol = bj << 7;
    const int wr = (w >> 1) << 6;        // wave row offset within tile
    const int wc = (w & 1) << 6;         // wave col offset within tile

    f32x4 acc[4][4];
    #pragma unroll
    for (int i = 0; i < 4; i++)
        #pragma unroll
        for (int j = 0; j < 4; j++) acc[i][j] = (f32x4)0.0f;

    // staging geometry (constant over kt)
    const int g_src = (l & 7) ^ (l >> 3);   // inverse-swizzled source 16B-group

    for (int kt = 0; kt < 8; kt++) {
        const int kbase = kt << 6;
        #pragma unroll
        for (int m = 0; m < 4; m++) {
            const int chunk = (w << 2) + m;           // 0..15
            const int r = (chunk << 3) + (l >> 3);    // tile row 0..127 (r&7 == l>>3)
            const size_t colb = (size_t)(kbase + (g_src << 3));
            gload16(E + (size_t)(brow + r) * DIM + colb, &lA[chunk << 9]);
            gload16(E + (size_t)(bcol + r) * DIM + colb, &lB[chunk << 9]);
        }
        __syncthreads();

        #pragma unroll
        for (int kk = 0; kk < 2; kk++) {
            bf16x8 aF[4], bF[4];
            const int gk = (kk << 2) + (l >> 4);      // 16B-group within row, 0..7
            const int gsw = (gk ^ (l & 7)) << 3;      // swizzled ushort offset in row
            #pragma unroll
            for (int mi = 0; mi < 4; mi++) {
                const int rr = wr + (mi << 4) + (l & 15);
                aF[mi] = *(const bf16x8*)&lA[(rr << 6) + gsw];
            }
            #pragma unroll
            for (int ni = 0; ni < 4; ni++) {
                const int rr = wc + (ni << 4) + (l & 15);
                bF[ni] = *(const bf16x8*)&lB[(rr << 6) + gsw];
            }
            #pragma unroll
            for (int mi = 0; mi < 4; mi++)
                #pragma unroll
                for (int ni = 0; ni < 4; ni++)
                    acc[mi][ni] = __builtin_amdgcn_mfma_f32_16x16x32_bf16(
                        aF[mi], bF[ni], acc[mi][ni], 0, 0, 0);
        }
        __syncthreads();
    }

    // ---- epilogue: exp((10*dot)-10), classify, per-row reduce, atomics ----
    const bool diagBlock = (bi == bj);
    #pragma unroll
    for (int mi = 0; mi < 4; mi++) {
        #pragma unroll
        for (int r = 0; r < 4; r++) {
            const int gi = brow + wr + (mi << 4) + ((l >> 4) << 2) + r;
            float p = 0.0f, n = 0.0f;
            #pragma unroll
            for (int ni = 0; ni < 4; ni++) {
                const int gj = bcol + wc + (ni << 4) + (l & 15);
                const float s = acc[mi][ni][r] * 10.0f;
                const float e = __expf(s - 10.0f);
                if (diagBlock) {
                    if (gi == gj) {
                        // self: excluded everywhere
                    } else if ((gi >> 2) == (gj >> 2)) {
                        p += e;
                    } else {
                        n += e;
                    }
                } else {
                    n += e;
                }
            }
            // reduce across the 16 lanes that share this row
            #pragma unroll
            for (int m = 1; m < 16; m <<= 1) {
                n += __shfl_xor(n, m);
                if (diagBlock) p += __shfl_xor(p, m);
            }
            if ((l & 15) == 0) {
                atomicAdd(&neg[gi], n);
                if (diagBlock) atomicAdd(&pos[gi], p);
            }
        }
    }
}

// ---------------- Kernel 3: final loss reduction ----------------
__global__ __launch_bounds__(256) void kloss(const float* __restrict__ pos,
                                             const float* __restrict__ neg,
                                             float* __restrict__ out) {
    const int tid = threadIdx.x;
    float s = 0.0f;
    for (int i = tid; i < NROWS; i += 256) {
        const float p = pos[i];
        const float n = neg[i];
        s += logf(p + n + 1e-8f) - logf(p);
    }
    #pragma unroll
    for (int m = 1; m < 64; m <<= 1) s += __shfl_xor(s, m);
    __shared__ float red[4];
    if ((tid & 63) == 0) red[tid >> 6] = s;
    __syncthreads();
    if (tid == 0) out[0] = (red[0] + red[1] + red[2] + red[3]) / (float)NROWS;
}

extern "C" void kernel_launch(void* const* d_in, const int* in_sizes, int n_in,
                              void* d_out, int out_size, void* d_ws, size_t ws_size,
                              hipStream_t stream) {
    (void)in_sizes; (void)n_in; (void)out_size; (void)ws_size;
    const float* emb = (const float*)d_in[0];
    unsigned short* En = (unsigned short*)d_ws;                       // 8 MB bf16
    float* pos = (float*)((char*)d_ws + (size_t)NROWS * DIM * 2);     // 32 KB
    float* neg = pos + NROWS;                                         // 32 KB

    hipMemsetAsync(pos, 0, (size_t)NROWS * 2 * sizeof(float), stream);
    knorm<<<NROWS / 4, 256, 0, stream>>>(emb, En);
    kgemm<<<64 * 64, 256, 0, stream>>>(En, pos, neg);
    kloss<<<1, 256, 0, stream>>>(pos, neg, (float*)d_out);
}

// Round 2
// 114.470 us; speedup vs baseline: 1.6557x; 1.6557x over previous
//
#include <hip/hip_runtime.h>
#include <hip/hip_bf16.h>
#include <stdint.h>

#define NROWS 8192
#define DIM 512

typedef short bf16x8 __attribute__((ext_vector_type(8)));
typedef float f32x4 __attribute__((ext_vector_type(4)));

__device__ __forceinline__ unsigned short f2bf(float f) {
    union { float f; uint32_t u; } c; c.f = f;
    uint32_t u = c.u;
    return (unsigned short)((u + 0x7FFFu + ((u >> 16) & 1u)) >> 16);
}

__device__ __forceinline__ void gload16(const unsigned short* g, unsigned short* l) {
    __builtin_amdgcn_global_load_lds((const __attribute__((address_space(1))) void*)g,
                                     (__attribute__((address_space(3))) void*)l,
                                     16, 0, 0);
}

// ---------------- Kernel 1: L2-normalize rows, emit bf16 ----------------
__global__ __launch_bounds__(256) void knorm(const float* __restrict__ in,
                                             unsigned short* __restrict__ out) {
    const int row  = (blockIdx.x << 2) + (threadIdx.x >> 6);
    const int lane = threadIdx.x & 63;
    const float4* src = (const float4*)(in + (size_t)row * DIM);
    float4 a = src[lane];
    float4 b = src[lane + 64];
    float ss = a.x*a.x + a.y*a.y + a.z*a.z + a.w*a.w
             + b.x*b.x + b.y*b.y + b.z*b.z + b.w*b.w;
    #pragma unroll
    for (int m = 1; m < 64; m <<= 1) ss += __shfl_xor(ss, m);
    const float inv = 1.0f / sqrtf(ss);
    ushort4* dst = (ushort4*)(out + (size_t)row * DIM);
    ushort4 o;
    o.x = f2bf(a.x*inv); o.y = f2bf(a.y*inv); o.z = f2bf(a.z*inv); o.w = f2bf(a.w*inv);
    dst[lane] = o;
    o.x = f2bf(b.x*inv); o.y = f2bf(b.y*inv); o.z = f2bf(b.z*inv); o.w = f2bf(b.w*inv);
    dst[lane + 64] = o;
}

// ---------------- Kernel 2: upper-triangle E*E^T + exp + mask + reduce ----------------
// Only blocks with bi <= bj are launched (2080 of 64x64). Off-diagonal blocks
// are pure negatives (positive groups of 4 never cross a 128 boundary) and
// contribute exp values to BOTH neg[gi] (row sums) and neg[gj] (col sums,
// valid because sim is symmetric). Diagonal blocks classify per element.
// Tile 128x128, 4 waves (2x2, each 64x64), BK=64, K=512.
// LDS: linear [128][64] bf16, XOR-swizzled on the 16B-group axis; source
// address inverse-swizzled so global_load_lds's linear write lands swizzled.
__global__ __launch_bounds__(256) void kgemm(const unsigned short* __restrict__ E,
                                             float* __restrict__ pos,
                                             float* __restrict__ neg) {
    __shared__ unsigned short lA[128 * 64];
    __shared__ unsigned short lB[128 * 64];

    const int tid = threadIdx.x;
    const int w = tid >> 6;
    const int l = tid & 63;

    // decode linear block id -> (bi, bj) with bi <= bj
    int bi = 0, rem = blockIdx.x;
    while (rem >= 64 - bi) { rem -= 64 - bi; bi++; }
    const int bj = bi + rem;

    const int brow = bi << 7;
    const int bcol = bj << 7;
    const int wr = (w >> 1) << 6;        // wave row offset within tile
    const int wc = (w & 1) << 6;         // wave col offset within tile

    f32x4 acc[4][4];
    #pragma unroll
    for (int i = 0; i < 4; i++)
        #pragma unroll
        for (int j = 0; j < 4; j++) acc[i][j] = (f32x4)0.0f;

    const int g_src = (l & 7) ^ (l >> 3);   // inverse-swizzled source 16B-group

    for (int kt = 0; kt < 8; kt++) {
        const int kbase = kt << 6;
        #pragma unroll
        for (int m = 0; m < 4; m++) {
            const int chunk = (w << 2) + m;           // 0..15
            const int r = (chunk << 3) + (l >> 3);    // tile row 0..127 (r&7 == l>>3)
            const size_t colb = (size_t)(kbase + (g_src << 3));
            gload16(E + (size_t)(brow + r) * DIM + colb, &lA[chunk << 9]);
            gload16(E + (size_t)(bcol + r) * DIM + colb, &lB[chunk << 9]);
        }
        __syncthreads();

        #pragma unroll
        for (int kk = 0; kk < 2; kk++) {
            bf16x8 aF[4], bF[4];
            const int gk = (kk << 2) + (l >> 4);      // 16B-group within row, 0..7
            const int gsw = (gk ^ (l & 7)) << 3;      // swizzled ushort offset in row
            #pragma unroll
            for (int mi = 0; mi < 4; mi++) {
                const int rr = wr + (mi << 4) + (l & 15);
                aF[mi] = *(const bf16x8*)&lA[(rr << 6) + gsw];
            }
            #pragma unroll
            for (int ni = 0; ni < 4; ni++) {
                const int rr = wc + (ni << 4) + (l & 15);
                bF[ni] = *(const bf16x8*)&lB[(rr << 6) + gsw];
            }
            #pragma unroll
            for (int mi = 0; mi < 4; mi++)
                #pragma unroll
                for (int ni = 0; ni < 4; ni++)
                    acc[mi][ni] = __builtin_amdgcn_mfma_f32_16x16x32_bf16(
                        aF[mi], bF[ni], acc[mi][ni], 0, 0, 0);
        }
        __syncthreads();
    }

    // ---- epilogue: exp((10*dot)-10), classify/scatter, reduce, atomics ----
    if (bi == bj) {
        // diagonal block: full 128x128 computed; classify each element
        #pragma unroll
        for (int mi = 0; mi < 4; mi++) {
            #pragma unroll
            for (int r = 0; r < 4; r++) {
                const int gi = brow + wr + (mi << 4) + ((l >> 4) << 2) + r;
                float p = 0.0f, n = 0.0f;
                #pragma unroll
                for (int ni = 0; ni < 4; ni++) {
                    const int gj = bcol + wc + (ni << 4) + (l & 15);
                    const float e = __expf(acc[mi][ni][r] * 10.0f - 10.0f);
                    if (gi == gj) {
                        // self: excluded
                    } else if ((gi >> 2) == (gj >> 2)) {
                        p += e;
                    } else {
                        n += e;
                    }
                }
                #pragma unroll
                for (int m = 1; m < 16; m <<= 1) {
                    n += __shfl_xor(n, m);
                    p += __shfl_xor(p, m);
                }
                if ((l & 15) == 0) {
                    atomicAdd(&neg[gi], n);
                    atomicAdd(&pos[gi], p);
                }
            }
        }
    } else {
        // off-diagonal: all negatives; scatter to rows (gi) and cols (gj)
        float c[4] = {0.0f, 0.0f, 0.0f, 0.0f};
        #pragma unroll
        for (int mi = 0; mi < 4; mi++) {
            #pragma unroll
            for (int r = 0; r < 4; r++) {
                const int gi = brow + wr + (mi << 4) + ((l >> 4) << 2) + r;
                float n = 0.0f;
                #pragma unroll
                for (int ni = 0; ni < 4; ni++) {
                    const float e = __expf(acc[mi][ni][r] * 10.0f - 10.0f);
                    n += e;
                    c[ni] += e;
                }
                #pragma unroll
                for (int m = 1; m < 16; m <<= 1) n += __shfl_xor(n, m);
                if ((l & 15) == 0) atomicAdd(&neg[gi], n);
            }
        }
        #pragma unroll
        for (int ni = 0; ni < 4; ni++) {
            c[ni] += __shfl_xor(c[ni], 16);
            c[ni] += __shfl_xor(c[ni], 32);
            if ((l >> 4) == 0) {
                const int gj = bcol + wc + (ni << 4) + (l & 15);
                atomicAdd(&neg[gj], c[ni]);
            }
        }
    }
}

// ---------------- Kernel 3: final loss reduction ----------------
__global__ __launch_bounds__(256) void kloss(const float* __restrict__ pos,
                                             const float* __restrict__ neg,
                                             float* __restrict__ out) {
    const int tid = threadIdx.x;
    float s = 0.0f;
    for (int i = tid; i < NROWS; i += 256) {
        const float p = pos[i];
        const float n = neg[i];
        s += logf(p + n + 1e-8f) - logf(p);
    }
    #pragma unroll
    for (int m = 1; m < 64; m <<= 1) s += __shfl_xor(s, m);
    __shared__ float red[4];
    if ((tid & 63) == 0) red[tid >> 6] = s;
    __syncthreads();
    if (tid == 0) out[0] = (red[0] + red[1] + red[2] + red[3]) / (float)NROWS;
}

extern "C" void kernel_launch(void* const* d_in, const int* in_sizes, int n_in,
                              void* d_out, int out_size, void* d_ws, size_t ws_size,
                              hipStream_t stream) {
    (void)in_sizes; (void)n_in; (void)out_size; (void)ws_size;
    const float* emb = (const float*)d_in[0];
    unsigned short* En = (unsigned short*)d_ws;                       // 8 MB bf16
    float* pos = (float*)((char*)d_ws + (size_t)NROWS * DIM * 2);     // 32 KB
    float* neg = pos + NROWS;                                         // 32 KB

    hipMemsetAsync(pos, 0, (size_t)NROWS * 2 * sizeof(float), stream);
    knorm<<<NROWS / 4, 256, 0, stream>>>(emb, En);
    kgemm<<<2080, 256, 0, stream>>>(En, pos, neg);
    kloss<<<1, 256, 0, stream>>>(pos, neg, (float*)d_out);
}

// Round 3
// 98.705 us; speedup vs baseline: 1.9201x; 1.1597x over previous
//
#include <hip/hip_runtime.h>
#include <hip/hip_bf16.h>
#include <stdint.h>

#define NROWS 8192
#define DIM 512

typedef short bf16x8 __attribute__((ext_vector_type(8)));
typedef float f32x4 __attribute__((ext_vector_type(4)));

__device__ __forceinline__ unsigned short f2bf(float f) {
    union { float f; uint32_t u; } c; c.f = f;
    uint32_t u = c.u;
    return (unsigned short)((u + 0x7FFFu + ((u >> 16) & 1u)) >> 16);
}

__device__ __forceinline__ void gload16(const unsigned short* g, unsigned short* l) {
    __builtin_amdgcn_global_load_lds((const __attribute__((address_space(1))) void*)g,
                                     (__attribute__((address_space(3))) void*)l,
                                     16, 0, 0);
}

// ---------------- Kernel 1: L2-normalize rows -> bf16; also zero pos/neg ----------------
__global__ __launch_bounds__(256) void knorm(const float* __restrict__ in,
                                             unsigned short* __restrict__ out,
                                             float* __restrict__ pos,
                                             float* __restrict__ neg) {
    const int row  = (blockIdx.x << 2) + (threadIdx.x >> 6);
    const int lane = threadIdx.x & 63;
    // zero accumulators (4 rows per block)
    if (threadIdx.x < 4)      pos[(blockIdx.x << 2) + threadIdx.x] = 0.0f;
    else if (threadIdx.x < 8) neg[(blockIdx.x << 2) + threadIdx.x - 4] = 0.0f;

    const float4* src = (const float4*)(in + (size_t)row * DIM);
    float4 a = src[lane];
    float4 b = src[lane + 64];
    float ss = a.x*a.x + a.y*a.y + a.z*a.z + a.w*a.w
             + b.x*b.x + b.y*b.y + b.z*b.z + b.w*b.w;
    #pragma unroll
    for (int m = 1; m < 64; m <<= 1) ss += __shfl_xor(ss, m);
    const float inv = 1.0f / sqrtf(ss);
    ushort4* dst = (ushort4*)(out + (size_t)row * DIM);
    ushort4 o;
    o.x = f2bf(a.x*inv); o.y = f2bf(a.y*inv); o.z = f2bf(a.z*inv); o.w = f2bf(a.w*inv);
    dst[lane] = o;
    o.x = f2bf(b.x*inv); o.y = f2bf(b.y*inv); o.z = f2bf(b.z*inv); o.w = f2bf(b.w*inv);
    dst[lane + 64] = o;
}

// ---------------- Kernel 2: upper-triangle E*E^T + exp + mask + reduce ----------------
// 256x256 tile, 8 waves (2Mx4N, each 128x64), BK=64, double-buffered LDS with
// 2-phase prefetch (issue next K-tile's global_load_lds before computing the
// current one; single __syncthreads()/vmcnt-drain per K-step).
// Triangle grid is 32x32 (bi<=bj), enumerated in 8x8 supertiles; linear block
// ids are partitioned contiguously per XCD (blockIdx%8) so each XCD's L2 sees
// a compact panel working set.
// LDS swizzle: linear dest (global_load_lds) + inverse-swizzled SOURCE address
// + same-XOR ds_read (proven 0-conflict in R0/R1).
__global__ __launch_bounds__(512, 2) void kgemm(const unsigned short* __restrict__ E,
                                                float* __restrict__ pos,
                                                float* __restrict__ neg) {
    __shared__ unsigned short lds[4][16384];   // [buf*2 + (0=A,1=B)][256 rows x 64]

    const int tid = threadIdx.x;
    const int w = tid >> 6;
    const int l = tid & 63;

    // ---- block id -> (bi, bj), XCD-partitioned supertile order ----
    int rem = (int)((blockIdx.x & 7) * 66 + (blockIdx.x >> 3));  // 528 = 8*66
    int SI = -1, SJ = -1;
    #pragma unroll
    for (int s = 0; s < 10; s++) {
        constexpr int si_t[10] = {0,0,0,0,1,1,1,2,2,3};
        constexpr int sj_t[10] = {0,1,2,3,1,2,3,2,3,3};
        const int sz = (si_t[s] == sj_t[s]) ? 36 : 64;
        if (SI < 0) {
            if (rem < sz) { SI = si_t[s]; SJ = sj_t[s]; }
            else rem -= sz;
        }
    }
    int bi, bj;
    if (SI == SJ) {
        int x = 0;
        while (rem >= 8 - x) { rem -= 8 - x; x++; }
        bi = (SI << 3) + x; bj = (SI << 3) + x + rem;
    } else {
        bi = (SI << 3) + (rem >> 3);
        bj = (SJ << 3) + (rem & 7);
    }

    const int brow = bi << 8;
    const int bcol = bj << 8;
    const int wr = (w >> 2) << 7;        // 0 or 128
    const int wc = (w & 3) << 6;         // 0,64,128,192

    f32x4 acc[8][4];
    #pragma unroll
    for (int i = 0; i < 8; i++)
        #pragma unroll
        for (int j = 0; j < 4; j++) acc[i][j] = (f32x4)0.0f;

    const int g_src = (l & 7) ^ (l >> 3);   // inverse-swizzled source 16B-group

    // ---- staging: 64 KB per K-step (A 32K + B 32K), 8 gload16 per wave ----
    auto STAGE = [&](int buf, int kt) {
        const size_t colb = (size_t)((kt << 6) + (g_src << 3));
        unsigned short* dA = lds[buf << 1];
        unsigned short* dB = lds[(buf << 1) + 1];
        #pragma unroll
        for (int m = 0; m < 4; m++) {
            const int chunk = (w << 2) + m;           // 0..31
            const int r = (chunk << 3) + (l >> 3);    // 0..255 (r&7 == l>>3)
            gload16(E + (size_t)(brow + r) * DIM + colb, &dA[chunk << 9]);
            gload16(E + (size_t)(bcol + r) * DIM + colb, &dB[chunk << 9]);
        }
    };

    auto COMPUTE = [&](int buf) {
        const unsigned short* sA = lds[buf << 1];
        const unsigned short* sB = lds[(buf << 1) + 1];
        #pragma unroll
        for (int kk = 0; kk < 2; kk++) {
            bf16x8 aF[8], bF[4];
            const int gk = (kk << 2) + (l >> 4);
            const int gsw = (gk ^ (l & 7)) << 3;
            #pragma unroll
            for (int mi = 0; mi < 8; mi++) {
                const int rr = wr + (mi << 4) + (l & 15);
                aF[mi] = *(const bf16x8*)&sA[(rr << 6) + gsw];
            }
            #pragma unroll
            for (int ni = 0; ni < 4; ni++) {
                const int rr = wc + (ni << 4) + (l & 15);
                bF[ni] = *(const bf16x8*)&sB[(rr << 6) + gsw];
            }
            #pragma unroll
            for (int mi = 0; mi < 8; mi++)
                #pragma unroll
                for (int ni = 0; ni < 4; ni++)
                    acc[mi][ni] = __builtin_amdgcn_mfma_f32_16x16x32_bf16(
                        aF[mi], bF[ni], acc[mi][ni], 0, 0, 0);
        }
    };

    STAGE(0, 0);
    __syncthreads();
    int cur = 0;
    for (int kt = 0; kt < 8; kt++) {
        if (kt < 7) STAGE(cur ^ 1, kt + 1);   // prefetch flies during compute
        COMPUTE(cur);
        __syncthreads();                       // drains vmcnt+lgkm, swaps safely
        cur ^= 1;
    }

    // ---- epilogue: exp(10*dot - 10), classify/scatter, reduce, atomics ----
    if (bi == bj) {
        #pragma unroll
        for (int mi = 0; mi < 8; mi++) {
            #pragma unroll
            for (int r = 0; r < 4; r++) {
                const int gi = brow + wr + (mi << 4) + ((l >> 4) << 2) + r;
                float p = 0.0f, n = 0.0f;
                #pragma unroll
                for (int ni = 0; ni < 4; ni++) {
                    const int gj = bcol + wc + (ni << 4) + (l & 15);
                    const float e = __expf(acc[mi][ni][r] * 10.0f - 10.0f);
                    if (gi == gj) {
                    } else if ((gi >> 2) == (gj >> 2)) {
                        p += e;
                    } else {
                        n += e;
                    }
                }
                #pragma unroll
                for (int m = 1; m < 16; m <<= 1) {
                    n += __shfl_xor(n, m);
                    p += __shfl_xor(p, m);
                }
                if ((l & 15) == 0) {
                    atomicAdd(&neg[gi], n);
                    atomicAdd(&pos[gi], p);
                }
            }
        }
    } else {
        float c[4] = {0.0f, 0.0f, 0.0f, 0.0f};
        #pragma unroll
        for (int mi = 0; mi < 8; mi++) {
            #pragma unroll
            for (int r = 0; r < 4; r++) {
                const int gi = brow + wr + (mi << 4) + ((l >> 4) << 2) + r;
                float n = 0.0f;
                #pragma unroll
                for (int ni = 0; ni < 4; ni++) {
                    const float e = __expf(acc[mi][ni][r] * 10.0f - 10.0f);
                    n += e;
                    c[ni] += e;
                }
                #pragma unroll
                for (int m = 1; m < 16; m <<= 1) n += __shfl_xor(n, m);
                if ((l & 15) == 0) atomicAdd(&neg[gi], n);
            }
        }
        #pragma unroll
        for (int ni = 0; ni < 4; ni++) {
            c[ni] += __shfl_xor(c[ni], 16);
            c[ni] += __shfl_xor(c[ni], 32);
            if ((l >> 4) == 0) {
                const int gj = bcol + wc + (ni << 4) + (l & 15);
                atomicAdd(&neg[gj], c[ni]);
            }
        }
    }
}

// ---------------- Kernel 3: final loss reduction ----------------
__global__ __launch_bounds__(1024) void kloss(const float* __restrict__ pos,
                                              const float* __restrict__ neg,
                                              float* __restrict__ out) {
    const int tid = threadIdx.x;
    float s = 0.0f;
    for (int i = tid; i < NROWS; i += 1024) {
        const float p = pos[i];
        const float n = neg[i];
        s += logf(p + n + 1e-8f) - logf(p);
    }
    #pragma unroll
    for (int m = 1; m < 64; m <<= 1) s += __shfl_xor(s, m);
    __shared__ float red[16];
    if ((tid & 63) == 0) red[tid >> 6] = s;
    __syncthreads();
    if (tid == 0) {
        float t = 0.0f;
        #pragma unroll
        for (int i = 0; i < 16; i++) t += red[i];
        out[0] = t / (float)NROWS;
    }
}

extern "C" void kernel_launch(void* const* d_in, const int* in_sizes, int n_in,
                              void* d_out, int out_size, void* d_ws, size_t ws_size,
                              hipStream_t stream) {
    (void)in_sizes; (void)n_in; (void)out_size; (void)ws_size;
    const float* emb = (const float*)d_in[0];
    unsigned short* En = (unsigned short*)d_ws;                       // 8 MB bf16
    float* pos = (float*)((char*)d_ws + (size_t)NROWS * DIM * 2);     // 32 KB
    float* neg = pos + NROWS;                                         // 32 KB

    knorm<<<NROWS / 4, 256, 0, stream>>>(emb, En, pos, neg);
    kgemm<<<528, 512, 0, stream>>>(En, pos, neg);
    kloss<<<1, 1024, 0, stream>>>(pos, neg, (float*)d_out);
}